// Round 12
// baseline (143.889 us; speedup 1.0000x reference)
//
#include <hip/hip_runtime.h>
#include <math.h>

// ===================== shared params/helpers =====================
#define NBIN   512
#define BEXT   64.0f          // bins cover [-64,64], width 0.25 (exact in f32)
#define WSLACK 0.02f          // covers d2 cancellation error + bin-edge fp slop
#define AWIN   4.0f           // phase-A fixed half-window in x
#define BTH1   1024           // build threads

__device__ __forceinline__ int bin1(float x) {
    int c = (int)floorf((x + BEXT) * 4.0f);
    return min(NBIN - 1, max(0, c));
}
// monotone float->uint fold (tiny negative d2 from rounding still ordered right)
__device__ __forceinline__ unsigned f2sort(float f) {
    int b = __float_as_int(f);
    return (unsigned)b ^ (0x80000000u | (unsigned)(b >> 31));
}
__device__ __forceinline__ float sort2f(unsigned u) {
    unsigned b = (u & 0x80000000u) ? (u ^ 0x80000000u) : ~u;
    return __uint_as_float(b);
}
__device__ __forceinline__ void ins3k(unsigned long long k,
                                      unsigned long long& k0,
                                      unsigned long long& k1,
                                      unsigned long long& k2) {
    const bool c0 = k < k0, c1 = k < k1, c2 = k < k2;
    k2 = c1 ? k1 : (c2 ? k : k2);
    k1 = c0 ? k0 : (c1 ? k : k1);
    k0 = c0 ? k  : k0;
}
__device__ __forceinline__ unsigned long long shfl_xor_u64(unsigned long long v, int m) {
    unsigned lo = (unsigned)v, hi = (unsigned)(v >> 32);
    lo = __shfl_xor((int)lo, m, 64);
    hi = __shfl_xor((int)hi, m, 64);
    return ((unsigned long long)hi << 32) | lo;
}

// ---- fused 1-D counting sort (r9-proven): blocks [0,B) points, [B,2B) queries ----
extern "C" __global__ void __launch_bounds__(BTH1)
build1d(const float* __restrict__ xyz, const float* __restrict__ nxyz,
        int mb, int nb,
        float4* __restrict__ ps, int* __restrict__ pidx,
        int* __restrict__ qord, int* __restrict__ boff,
        int* __restrict__ ovf_cnt)
{
    __shared__ int hist[NBIN];
    __shared__ int scanb[NBIN];
    const int B    = (int)gridDim.x / 2;
    const bool isQ = (int)blockIdx.x >= B;
    const int b    = isQ ? (int)blockIdx.x - B : (int)blockIdx.x;
    const int tid  = threadIdx.x;
    const int n    = isQ ? nb : mb;
    const float* P = (isQ ? nxyz : xyz) + (size_t)b * n * 3;

    if (blockIdx.x == 0 && tid < B) ovf_cnt[tid] = 0;

    if (tid < NBIN) hist[tid] = 0;
    __syncthreads();
    for (int i = tid; i < n; i += BTH1) atomicAdd(&hist[bin1(P[i * 3])], 1);
    __syncthreads();
    int h = 0;
    if (tid < NBIN) { h = hist[tid]; scanb[tid] = h; }
    __syncthreads();
    for (int off = 1; off < NBIN; off <<= 1) {
        int t = 0;
        if (tid < NBIN && tid >= off) t = scanb[tid - off];
        __syncthreads();
        if (tid < NBIN) scanb[tid] += t;
        __syncthreads();
    }
    if (tid < NBIN) {
        const int excl = scanb[tid] - h;
        if (!isQ) {
            boff[(size_t)b * (NBIN + 1) + tid] = excl;
            if (tid == NBIN - 1) boff[(size_t)b * (NBIN + 1) + NBIN] = n;
        }
        hist[tid] = excl;
    }
    __syncthreads();
    for (int i = tid; i < n; i += BTH1) {
        const float x = P[i * 3], y = P[i * 3 + 1], z = P[i * 3 + 2];
        const int c = bin1(x);
        const int pos = atomicAdd(&hist[c], 1);
        if (isQ) {
            qord[(size_t)b * nb + pos] = i;
        } else {
            float pn;
            {
#pragma clang fp contract(off)
                pn = (x * x + y * y) + z * z;  // matches np.sum(known*known,-1)
            }
            ps[(size_t)b * mb + pos]   = make_float4(x, y, z, pn);
            pidx[(size_t)b * mb + pos] = i;    // original (tie-break) index
        }
    }
}

// ===================== phase A: fixed-window, per-query resolve (r11-proven) ==========
#define QWA  8                // queries per wave (lane&7 = query)
#define SWA  8                // sides (lane>>3), stride-8 interleave -> conflict-free
#define WVBA 4                // waves per block
#define WTHA (WVBA * 64)      // 256 threads
#define QPBA (WVBA * QWA)     // 32 queries per block
#define CHA  64               // candidates staged per chunk

extern "C" __global__ void __launch_bounds__(WTHA)
knn_phaseA(const float* __restrict__ nxyz, const float* __restrict__ feats,
           const int* __restrict__ qord, const int* __restrict__ boff,
           const float4* __restrict__ ps, const int* __restrict__ pidx,
           float* __restrict__ out, int* __restrict__ ovf, int* __restrict__ ovf_cnt,
           int mb, int nb, int C)
{
    __shared__ float4 sP[WVBA][CHA];
    __shared__ int    sI[WVBA][CHA];

    const int tid  = threadIdx.x;
    const int w    = tid >> 6;
    const int l    = tid & 63;
    const int qi   = l & 7;
    const int side = l >> 3;           // 0..7
    const int wid  = blockIdx.x * WVBA + w;
    const int q0   = wid * QWA;
    const int b    = q0 / nb;

    const int qloc = qord[q0 + qi];
    const int row  = b * nb + qloc;
    const float qx = nxyz[(size_t)row * 3 + 0];
    const float qy = nxyz[(size_t)row * 3 + 1];
    const float qz = nxyz[(size_t)row * 3 + 2];
    float qq;
    {
#pragma clang fp contract(off)
        qq = (qx * qx + qy * qy) + qz * qz;    // matches np.sum(query*query,-1)
    }

    // wave x-range (sides duplicate queries -> full butterfly fine)
    float mn = qx, mx = qx;
#pragma unroll
    for (int m = 1; m < 64; m <<= 1) {
        mn = fminf(mn, __shfl_xor(mn, m, 64));
        mx = fmaxf(mx, __shfl_xor(mx, m, 64));
    }

    const int*    boffb = boff + (size_t)b * (NBIN + 1);
    const float4* psb   = ps   + (size_t)b * mb;
    const int*    pib   = pidx + (size_t)b * mb;

    unsigned long long k0 = ~0ull, k1 = ~0ull, k2 = ~0ull;

    // one-chunk-ahead staging (proven schedule)
    float4 rP;
    int    rI = 0;
    bool   rV = false;
    auto issue = [&](int base, int hi) {
        const int cand = base + l;
        rV = cand < hi;
        if (rV) { rP = psb[cand]; rI = pib[cand]; }
    };
    auto commit = [&]() {
        if (rV) { sP[w][l] = rP; sI[w][l] = rI; }
    };
    auto process = [&](int cnt) {
#pragma unroll
        for (int u = 0; u < CHA / SWA; ++u) {
            const int j = side + u * SWA;          // stride-8: conflict-free broadcast
            if (j < cnt) {
                const float4 Pt = sP[w][j];
                const int    pi = sI[w][j];
                const float dot = fmaf(qz, Pt.z, fmaf(qy, Pt.y, qx * Pt.x));
                const float d2  = fmaf(-2.0f, dot, qq) + Pt.w;  // EXACT ref rounding
                const unsigned long long key =
                    ((unsigned long long)f2sort(d2) << 32) | (unsigned)pi;
                if (key < k2) {                    // rare after warm-up
                    const bool c0 = key < k0, c1 = key < k1;
                    k2 = c1 ? k1 : key;
                    k1 = c0 ? k0 : (c1 ? key : k1);
                    k0 = c0 ? key : k0;
                }
            }
        }
    };

    // fixed window [mn-AWIN, mx+AWIN]
    const int blo = bin1(mn - AWIN);
    const int bhi = bin1(mx + AWIN);
    {
        const int lo = boffb[blo], hi = boffb[bhi + 1];
        if (lo < hi) {
            issue(lo, hi);
            for (int base = lo; base < hi; base += CHA) {
                commit();
                if (base + CHA < hi) issue(base + CHA, hi);
                process(min(CHA, hi - base));
            }
        }
    }

    // 8-side butterfly merge (xor 8,16,32) -> every lane holds window top-3
    unsigned long long m0 = k0, m1 = k1, m2 = k2;
#pragma unroll
    for (int mk = 8; mk <= 32; mk <<= 1) {
        const unsigned long long t0 = shfl_xor_u64(m0, mk);
        const unsigned long long t1 = shfl_xor_u64(m1, mk);
        const unsigned long long t2 = shfl_xor_u64(m2, mk);
        ins3k(t0, m0, m1, m2); ins3k(t1, m0, m1, m2); ins3k(t2, m0, m1, m2);
    }

    // per-query provability: everything outside window is farther than ub
    const unsigned h2 = (unsigned)(m2 >> 32);
    const float ub = (h2 == 0xFFFFFFFFu) ? INFINITY : sort2f(h2);
    const float eL = fmaf(0.25f, (float)blo, -BEXT);       // exact bin edges
    const float eR = fmaf(0.25f, (float)(bhi + 1), -BEXT);
    const float gL = qx - eL;
    const float gR = eR - qx;
    const bool okL = (blo == 0)        || (gL * gL > ub + WSLACK);
    const bool okR = (bhi >= NBIN - 1) || (gR * gR > ub + WSLACK);
    const bool resolved = okL && okR && (h2 != 0xFFFFFFFFu);

    // append unresolved queries (one vote per query: side 0 == lanes 0..7)
    const bool need = (side == 0) && !resolved;
    const unsigned long long bm = __ballot(need);
    if (bm) {
        const int rank = __popcll(bm & ((1ull << l) - 1ull));
        const int tot  = __popcll(bm);
        const int lead = __ffsll((unsigned long long)bm) - 1;
        int base = 0;
        if (l == lead) base = atomicAdd(&ovf_cnt[b], tot);
        base = __shfl(base, lead, 64);
        if (need) ovf[(size_t)b * nb + base + rank] = row;
    }

    // weights for resolved queries
    const float d0  = sort2f((unsigned)(m0 >> 32));
    const float d1  = sort2f((unsigned)(m1 >> 32));
    const float d2v = sort2f((unsigned)(m2 >> 32));
    const float da = sqrtf(fmaxf(d0, 0.0f));
    const float db = sqrtf(fmaxf(d1, 0.0f));
    const float dc = sqrtf(fmaxf(d2v, 0.0f));
    const float ra = 1.0f / (da + 1e-8f);
    const float rb = 1.0f / (db + 1e-8f);
    const float rc = 1.0f / (dc + 1e-8f);
    float rs;
    {
#pragma clang fp contract(off)
        rs = (ra + rb) + rc;
    }
    const float wa = ra / rs, wb = rb / rs, wc = rc / rs;
    const int   ia = b * mb + (int)(unsigned)(m0 & 0xFFFFFFFFu);
    const int   ib = b * mb + (int)(unsigned)(m1 & 0xFFFFFFFFu);
    const int   ic = b * mb + (int)(unsigned)(m2 & 0xFFFFFFFFu);

    // fused interpolation: shfl-broadcast per query (lane q == side-0 of query q)
    for (int q = 0; q < QWA; ++q) {
        if (__shfl((int)resolved, q, 64) == 0) continue;
        const float wa_ = __shfl(wa, q, 64);
        const float wb_ = __shfl(wb, q, 64);
        const float wc_ = __shfl(wc, q, 64);
        const int   ia_ = __shfl(ia, q, 64);
        const int   ib_ = __shfl(ib, q, 64);
        const int   ic_ = __shfl(ic, q, 64);
        const int   rw_ = __shfl(row, q, 64);
        const size_t ga = (size_t)ia_ * C;
        const size_t gb = (size_t)ib_ * C;
        const size_t gc = (size_t)ic_ * C;
        const size_t go = (size_t)rw_ * C;
        for (int ch = l; ch < C; ch += 64) {
            out[go + ch] = wa_ * feats[ga + ch] + wb_ * feats[gb + ch] + wc_ * feats[gc + ch];
        }
    }
}

// ===================== phase B: exact brute over overflow, contiguous + early-exit ====
#define BQB  64               // contiguous overflow queries per block (lane = query)
#define BTHB 1024             // 16 waves
#define BCH  1024             // staged points per chunk

extern "C" __global__ void __launch_bounds__(BTHB)
knn_phaseB(const float* __restrict__ nxyz, const float* __restrict__ feats,
           const int* __restrict__ ovf, const int* __restrict__ ovf_cnt,
           const float4* __restrict__ ps, const int* __restrict__ pidx,
           float* __restrict__ out, int mb, int nb, int C)
{
    __shared__ float4 sPt[BCH];
    __shared__ int    sIx[BCH];
    __shared__ unsigned long long sK[16][3][BQB];
    __shared__ float sW[3][BQB];
    __shared__ int   sF[3][BQB];
    __shared__ int   sRow[BQB];
    __shared__ int   sAct[BQB];

    const int gpb   = nb / BQB;                // query-groups per batch
    const int bb    = (int)blockIdx.x / gpb;
    const int k     = (int)blockIdx.x % gpb;
    const int cnt   = ovf_cnt[bb];
    const int start = k * BQB;
    if (start >= cnt) return;                  // inactive block: exit fast

    const int tid = threadIdx.x;
    const int w   = tid >> 6;                  // 0..15
    const int l   = tid & 63;
    const float4* psb = ps   + (size_t)bb * mb;
    const int*    pib = pidx + (size_t)bb * mb;

    const int pos = start + l;
    const bool act = pos < cnt;
    const int row = act ? ovf[(size_t)bb * nb + pos] : bb * nb;   // dummy = valid row
    const float qx = nxyz[(size_t)row * 3 + 0];
    const float qy = nxyz[(size_t)row * 3 + 1];
    const float qz = nxyz[(size_t)row * 3 + 2];
    float qq;
    {
#pragma clang fp contract(off)
        qq = (qx * qx + qy * qy) + qz * qz;
    }
    if (w == 0) { sRow[l] = row; sAct[l] = act ? 1 : 0; }

    unsigned long long k0 = ~0ull, k1 = ~0ull, k2 = ~0ull;
    for (int base = 0; base < mb; base += BCH) {
        const int cc = min(BCH, mb - base);
        if (base > 0) __syncthreads();
        for (int i = tid; i < cc; i += BTHB) {
            sPt[i] = psb[base + i];
            sIx[i] = pib[base + i];
        }
        __syncthreads();
        const int lo = (w * cc) >> 4;
        const int hi = ((w + 1) * cc) >> 4;
#pragma unroll 4
        for (int pp = lo; pp < hi; ++pp) {
            const float4 Pt = sPt[pp];         // broadcast
            const int    pi = sIx[pp];
            const float dot = fmaf(qz, Pt.z, fmaf(qy, Pt.y, qx * Pt.x));
            const float d2  = fmaf(-2.0f, dot, qq) + Pt.w;   // EXACT ref rounding
            const unsigned long long key =
                ((unsigned long long)f2sort(d2) << 32) | (unsigned)pi;
            if (key < k2) {
                const bool c0 = key < k0, c1 = key < k1;
                k2 = c1 ? k1 : key;
                k1 = c0 ? k0 : (c1 ? key : k1);
                k0 = c0 ? key : k0;
            }
        }
    }
    __syncthreads();
    sK[w][0][l] = k0; sK[w][1][l] = k1; sK[w][2][l] = k2;
    __syncthreads();

    if (tid < BQB) {
        unsigned long long m0 = sK[0][0][tid], m1 = sK[0][1][tid], m2 = sK[0][2][tid];
#pragma unroll
        for (int w2 = 1; w2 < 16; ++w2) {
            ins3k(sK[w2][0][tid], m0, m1, m2);
            ins3k(sK[w2][1][tid], m0, m1, m2);
            ins3k(sK[w2][2][tid], m0, m1, m2);
        }
        const float d0  = sort2f((unsigned)(m0 >> 32));
        const float d1  = sort2f((unsigned)(m1 >> 32));
        const float d2v = sort2f((unsigned)(m2 >> 32));
        const float da = sqrtf(fmaxf(d0, 0.0f));
        const float db = sqrtf(fmaxf(d1, 0.0f));
        const float dc = sqrtf(fmaxf(d2v, 0.0f));
        const float ra = 1.0f / (da + 1e-8f);
        const float rb = 1.0f / (db + 1e-8f);
        const float rc = 1.0f / (dc + 1e-8f);
        float rsum;
        {
#pragma clang fp contract(off)
            rsum = (ra + rb) + rc;
        }
        sW[0][tid] = ra / rsum;  sW[1][tid] = rb / rsum;  sW[2][tid] = rc / rsum;
        sF[0][tid] = bb * mb + (int)(unsigned)(m0 & 0xFFFFFFFFu);
        sF[1][tid] = bb * mb + (int)(unsigned)(m1 & 0xFFFFFFFFu);
        sF[2][tid] = bb * mb + (int)(unsigned)(m2 & 0xFFFFFFFFu);
    }
    __syncthreads();

    // interpolation: 16 waves x 4 queries, lanes = channels
    for (int j = 0; j < BQB / 16; ++j) {
        const int q = w * (BQB / 16) + j;
        if (!sAct[q]) continue;
        const float wa = sW[0][q], wb = sW[1][q], wc = sW[2][q];
        const size_t ga = (size_t)sF[0][q] * C;
        const size_t gb = (size_t)sF[1][q] * C;
        const size_t gc = (size_t)sF[2][q] * C;
        const size_t go = (size_t)sRow[q] * C;
        for (int ch = l; ch < C; ch += 64) {
            out[go + ch] = wa * feats[ga + ch] + wb * feats[gb + ch] + wc * feats[gc + ch];
        }
    }
}

// ===================== fallback: round-5 brute (proven, shape-general) =====================
#define THREADS 512
#define WAVES   8
#define RQ      2
#define QPB     128
#define CHUNK   2048

extern "C" __global__ void __launch_bounds__(THREADS)
knn3_v5(const float* __restrict__ xyz,
        const float* __restrict__ new_xyz,
        const float* __restrict__ feats,
        float* __restrict__ out,
        int mb, int nb, int C)
{
    extern __shared__ float smem[];
    float4* s_pts = (float4*)smem;
    const int tid = threadIdx.x;
    const int w   = tid >> 6;
    const int l   = tid & 63;
    const int block_q0 = blockIdx.x * QPB;
    const int batch    = block_q0 / nb;
    const int known0   = batch * mb;

    float qx[RQ], qy[RQ], qz[RQ], qq[RQ];
#pragma unroll
    for (int r = 0; r < RQ; ++r) {
        const int gq = block_q0 + r * 64 + l;
        qx[r] = new_xyz[(size_t)gq * 3 + 0];
        qy[r] = new_xyz[(size_t)gq * 3 + 1];
        qz[r] = new_xyz[(size_t)gq * 3 + 2];
        {
#pragma clang fp contract(off)
            qq[r] = (qx[r] * qx[r] + qy[r] * qy[r]) + qz[r] * qz[r];
        }
    }
    float b0[RQ], b1[RQ], b2[RQ];
    int   i0[RQ], i1[RQ], i2[RQ];
#pragma unroll
    for (int r = 0; r < RQ; ++r) {
        b0[r] = INFINITY; b1[r] = INFINITY; b2[r] = INFINITY;
        i0[r] = 0; i1[r] = 0; i2[r] = 0;
    }
    const int nch = (mb + CHUNK - 1) / CHUNK;
    for (int c = 0; c < nch; ++c) {
        const int base = c * CHUNK;
        const int cnt  = min(CHUNK, mb - base);
        if (c > 0) __syncthreads();
        const float* src = xyz + (size_t)(known0 + base) * 3;
        for (int p = tid; p < cnt; p += THREADS) {
            const float px = src[p * 3 + 0];
            const float py = src[p * 3 + 1];
            const float pz = src[p * 3 + 2];
            float pn;
            {
#pragma clang fp contract(off)
                pn = (px * px + py * py) + pz * pz;
            }
            s_pts[p] = make_float4(px, py, pz, pn);
        }
        __syncthreads();
        const int lo = (w * cnt) / WAVES;
        const int hi = ((w + 1) * cnt) / WAVES;
#pragma unroll 4
        for (int p = lo; p < hi; ++p) {
            const float4 P = s_pts[p];
            const int gp = base + p;
#pragma unroll
            for (int r = 0; r < RQ; ++r) {
                const float dot = fmaf(qz[r], P.z, fmaf(qy[r], P.y, qx[r] * P.x));
                const float d2  = fmaf(-2.0f, dot, qq[r]) + P.w;
                const bool c0 = d2 < b0[r];
                const bool c1 = d2 < b1[r];
                const bool c2 = d2 < b2[r];
                const float n0 = fminf(d2, b0[r]);
                const float n1 = __builtin_amdgcn_fmed3f(d2, b0[r], b1[r]);
                const float n2 = __builtin_amdgcn_fmed3f(d2, b1[r], b2[r]);
                const int  j0 = c0 ? gp : i0[r];
                const int  j1 = c0 ? i0[r] : (c1 ? gp : i1[r]);
                const int  j2 = c1 ? i1[r] : (c2 ? gp : i2[r]);
                b0[r] = n0; b1[r] = n1; b2[r] = n2;
                i0[r] = j0; i1[r] = j1; i2[r] = j2;
            }
        }
    }
    __syncthreads();
    float* sB  = smem;
    int*   sI  = (int*)smem + 3 * WAVES * QPB;
    float* sFW = smem + 6 * WAVES * QPB;
    int*   sFI = (int*)sFW + 3 * QPB;
#pragma unroll
    for (int r = 0; r < RQ; ++r) {
        const int qb = r * 64 + l;
        sB[(0 * WAVES + w) * QPB + qb] = b0[r];
        sB[(1 * WAVES + w) * QPB + qb] = b1[r];
        sB[(2 * WAVES + w) * QPB + qb] = b2[r];
        sI[(0 * WAVES + w) * QPB + qb] = i0[r];
        sI[(1 * WAVES + w) * QPB + qb] = i1[r];
        sI[(2 * WAVES + w) * QPB + qb] = i2[r];
    }
    __syncthreads();
    if (tid < QPB) {
        float mv0 = sB[(0 * WAVES) * QPB + tid];
        float mv1 = sB[(1 * WAVES) * QPB + tid];
        float mv2 = sB[(2 * WAVES) * QPB + tid];
        int   mi0 = sI[(0 * WAVES) * QPB + tid];
        int   mi1 = sI[(1 * WAVES) * QPB + tid];
        int   mi2 = sI[(2 * WAVES) * QPB + tid];
        for (int c = 1; c < WAVES; ++c) {
#pragma unroll
            for (int kk = 0; kk < 3; ++kk) {
                const float x  = sB[(kk * WAVES + c) * QPB + tid];
                const int   xi = sI[(kk * WAVES + c) * QPB + tid];
                const bool c0 = (x < mv0) || (x == mv0 && xi < mi0);
                const bool c1 = (x < mv1) || (x == mv1 && xi < mi1);
                const bool c2 = (x < mv2) || (x == mv2 && xi < mi2);
                const float n2 = c1 ? mv1 : (c2 ? x : mv2);
                const int   j2 = c1 ? mi1 : (c2 ? xi : mi2);
                const float n1 = c0 ? mv0 : (c1 ? x : mv1);
                const int   j1 = c0 ? mi0 : (c1 ? xi : mi1);
                const float n0 = c0 ? x : mv0;
                const int   j0 = c0 ? xi : mi0;
                mv0 = n0; mv1 = n1; mv2 = n2;
                mi0 = j0; mi1 = j1; mi2 = j2;
            }
        }
        const float da = sqrtf(fmaxf(mv0, 0.0f));
        const float db = sqrtf(fmaxf(mv1, 0.0f));
        const float dc = sqrtf(fmaxf(mv2, 0.0f));
        const float ra = 1.0f / (da + 1e-8f);
        const float rb = 1.0f / (db + 1e-8f);
        const float rc = 1.0f / (dc + 1e-8f);
        float rsum;
        {
#pragma clang fp contract(off)
            rsum = (ra + rb) + rc;
        }
        sFW[0 * QPB + tid] = ra / rsum;
        sFW[1 * QPB + tid] = rb / rsum;
        sFW[2 * QPB + tid] = rc / rsum;
        sFI[0 * QPB + tid] = known0 + mi0;
        sFI[1 * QPB + tid] = known0 + mi1;
        sFI[2 * QPB + tid] = known0 + mi2;
    }
    __syncthreads();
    const int qpw = QPB / WAVES;
    for (int j = 0; j < qpw; ++j) {
        const int qi2 = w * qpw + j;
        const float wa = sFW[0 * QPB + qi2];
        const float wb = sFW[1 * QPB + qi2];
        const float wc = sFW[2 * QPB + qi2];
        const size_t ga = (size_t)sFI[0 * QPB + qi2] * C;
        const size_t gb = (size_t)sFI[1 * QPB + qi2] * C;
        const size_t gc = (size_t)sFI[2 * QPB + qi2] * C;
        const size_t go = (size_t)(block_q0 + qi2) * C;
        for (int ch = l; ch < C; ch += 64) {
            out[go + ch] = wa * feats[ga + ch] + wb * feats[gb + ch] + wc * feats[gc + ch];
        }
    }
}

#define FQPB 256
extern "C" __global__ void __launch_bounds__(FQPB)
knn3_fallback(const float* __restrict__ xyz,
              const float* __restrict__ new_xyz,
              const float* __restrict__ feats,
              float* __restrict__ out,
              int mb, int nb, int C)
{
    extern __shared__ float4 s_pts[];
    const int tid      = threadIdx.x;
    const int block_q0 = blockIdx.x * FQPB;
    const int batch    = block_q0 / nb;
    const int known0   = batch * mb;
    for (int p = tid; p < mb; p += FQPB) {
        const float px = xyz[(size_t)(known0 + p) * 3 + 0];
        const float py = xyz[(size_t)(known0 + p) * 3 + 1];
        const float pz = xyz[(size_t)(known0 + p) * 3 + 2];
        float pn;
        {
#pragma clang fp contract(off)
            pn = (px * px + py * py) + pz * pz;
        }
        s_pts[p] = make_float4(px, py, pz, pn);
    }
    __syncthreads();
    const int gq = block_q0 + tid;
    const float qx = new_xyz[(size_t)gq * 3 + 0];
    const float qy = new_xyz[(size_t)gq * 3 + 1];
    const float qz = new_xyz[(size_t)gq * 3 + 2];
    float qq;
    {
#pragma clang fp contract(off)
        qq = (qx * qx + qy * qy) + qz * qz;
    }
    float b0 = INFINITY, b1 = INFINITY, b2 = INFINITY;
    int   i0 = 0, i1 = 0, i2 = 0;
#pragma unroll 8
    for (int p = 0; p < mb; ++p) {
        const float4 P = s_pts[p];
        const float dot = fmaf(qz, P.z, fmaf(qy, P.y, qx * P.x));
        const float d2  = fmaf(-2.0f, dot, qq) + P.w;
        const bool c0 = d2 < b0;
        const bool c1 = d2 < b1;
        const bool c2 = d2 < b2;
        b2 = c1 ? b1 : (c2 ? d2 : b2);
        i2 = c1 ? i1 : (c2 ? p  : i2);
        b1 = c0 ? b0 : (c1 ? d2 : b1);
        i1 = c0 ? i0 : (c1 ? p  : i1);
        b0 = c0 ? d2 : b0;
        i0 = c0 ? p  : i0;
    }
    const float da = sqrtf(fmaxf(b0, 0.0f));
    const float db = sqrtf(fmaxf(b1, 0.0f));
    const float dc = sqrtf(fmaxf(b2, 0.0f));
    const float ra = 1.0f / (da + 1e-8f);
    const float rb = 1.0f / (db + 1e-8f);
    const float rc = 1.0f / (dc + 1e-8f);
    float rsum;
    {
#pragma clang fp contract(off)
        rsum = (ra + rb) + rc;
    }
    const float wa = ra / rsum, wb = rb / rsum, wc = rc / rsum;
    const size_t ga = (size_t)(known0 + i0) * C;
    const size_t gb = (size_t)(known0 + i1) * C;
    const size_t gc = (size_t)(known0 + i2) * C;
    const size_t go = (size_t)gq * C;
    for (int ch = 0; ch < C; ++ch) {
        out[go + ch] = wa * feats[ga + ch] + wb * feats[gb + ch] + wc * feats[gc + ch];
    }
}

extern "C" void kernel_launch(void* const* d_in, const int* in_sizes, int n_in,
                              void* d_out, int out_size, void* d_ws, size_t ws_size,
                              hipStream_t stream) {
    const float* xyz     = (const float*)d_in[0];
    const float* new_xyz = (const float*)d_in[2];
    const float* feats   = (const float*)d_in[4];
    float*       out     = (float*)d_out;

    const int n_known = in_sizes[0] / 3;
    const int B       = in_sizes[1];
    const int n_query = in_sizes[2] / 3;
    const int C       = in_sizes[4] / n_known;
    const int mb      = n_known / B;
    const int nb      = n_query / B;

    // workspace layout
    char* wp = (char*)d_ws;
    float4* ps      = (float4*)wp;  wp += (size_t)B * mb * sizeof(float4);
    int*    pidx    = (int*)wp;     wp += (size_t)B * mb * sizeof(int);
    int*    qord    = (int*)wp;     wp += (size_t)B * nb * sizeof(int);
    int*    boff    = (int*)wp;     wp += (size_t)B * (NBIN + 1) * sizeof(int);
    int*    ovf     = (int*)wp;     wp += (size_t)B * nb * sizeof(int);
    int*    ovf_cnt = (int*)wp;     wp += (size_t)B * sizeof(int);
    const size_t need = (size_t)(wp - (char*)d_ws);

    if (ws_size >= need && (nb % QWA) == 0 && (n_query % QPBA) == 0 &&
        (nb % BQB) == 0 && mb >= 3 && B <= BTH1) {
        build1d<<<2 * B, BTH1, 0, stream>>>(xyz, new_xyz, mb, nb, ps, pidx, qord,
                                            boff, ovf_cnt);
        knn_phaseA<<<n_query / QPBA, WTHA, 0, stream>>>(
            new_xyz, feats, qord, boff, ps, pidx, out, ovf, ovf_cnt, mb, nb, C);
        knn_phaseB<<<B * (nb / BQB), BTHB, 0, stream>>>(
            new_xyz, feats, ovf, ovf_cnt, ps, pidx, out, mb, nb, C);
    } else if ((nb % QPB) == 0) {
        const size_t smem_chunk = (size_t)CHUNK * sizeof(float4);
        const size_t smem_merge = (size_t)(6 * WAVES * QPB + 6 * QPB) * sizeof(float);
        const size_t shmem = smem_chunk > smem_merge ? smem_chunk : smem_merge;
        knn3_v5<<<n_query / QPB, THREADS, shmem, stream>>>(
            xyz, new_xyz, feats, out, mb, nb, C);
    } else {
        const size_t shmem = (size_t)mb * sizeof(float4);
        knn3_fallback<<<(n_query + FQPB - 1) / FQPB, FQPB, shmem, stream>>>(
            xyz, new_xyz, feats, out, mb, nb, C);
    }
}

// Round 13
// 96.132 us; speedup vs baseline: 1.4968x; 1.4968x over previous
//
#include <hip/hip_runtime.h>
#include <math.h>

// ===================== shared params/helpers =====================
#define NBIN   512
#define BEXT   64.0f          // bins cover [-64,64], width 0.25 (exact in f32)
#define WSLACK 0.02f          // covers d2 cancellation error + bin-edge fp slop
#define AWIN   4.0f           // phase-A fixed half-window in x
#define BTH1   1024           // build threads

__device__ __forceinline__ int bin1(float x) {
    int c = (int)floorf((x + BEXT) * 4.0f);
    return min(NBIN - 1, max(0, c));
}
// monotone float->uint fold (tiny negative d2 from rounding still ordered right)
__device__ __forceinline__ unsigned f2sort(float f) {
    int b = __float_as_int(f);
    return (unsigned)b ^ (0x80000000u | (unsigned)(b >> 31));
}
__device__ __forceinline__ float sort2f(unsigned u) {
    unsigned b = (u & 0x80000000u) ? (u ^ 0x80000000u) : ~u;
    return __uint_as_float(b);
}
__device__ __forceinline__ void ins3k(unsigned long long k,
                                      unsigned long long& k0,
                                      unsigned long long& k1,
                                      unsigned long long& k2) {
    const bool c0 = k < k0, c1 = k < k1, c2 = k < k2;
    k2 = c1 ? k1 : (c2 ? k : k2);
    k1 = c0 ? k0 : (c1 ? k : k1);
    k0 = c0 ? k  : k0;
}
__device__ __forceinline__ unsigned long long shfl_xor_u64(unsigned long long v, int m) {
    unsigned lo = (unsigned)v, hi = (unsigned)(v >> 32);
    lo = __shfl_xor((int)lo, m, 64);
    hi = __shfl_xor((int)hi, m, 64);
    return ((unsigned long long)hi << 32) | lo;
}

// ---- fused 1-D counting sort (r9-proven): blocks [0,B) points, [B,2B) queries ----
extern "C" __global__ void __launch_bounds__(BTH1)
build1d(const float* __restrict__ xyz, const float* __restrict__ nxyz,
        int mb, int nb,
        float4* __restrict__ ps, int* __restrict__ pidx,
        int* __restrict__ qord, int* __restrict__ boff,
        int* __restrict__ ovf_cnt)
{
    __shared__ int hist[NBIN];
    __shared__ int scanb[NBIN];
    const int B    = (int)gridDim.x / 2;
    const bool isQ = (int)blockIdx.x >= B;
    const int b    = isQ ? (int)blockIdx.x - B : (int)blockIdx.x;
    const int tid  = threadIdx.x;
    const int n    = isQ ? nb : mb;
    const float* P = (isQ ? nxyz : xyz) + (size_t)b * n * 3;

    if (blockIdx.x == 0 && tid < B) ovf_cnt[tid] = 0;

    if (tid < NBIN) hist[tid] = 0;
    __syncthreads();
    for (int i = tid; i < n; i += BTH1) atomicAdd(&hist[bin1(P[i * 3])], 1);
    __syncthreads();
    int h = 0;
    if (tid < NBIN) { h = hist[tid]; scanb[tid] = h; }
    __syncthreads();
    for (int off = 1; off < NBIN; off <<= 1) {
        int t = 0;
        if (tid < NBIN && tid >= off) t = scanb[tid - off];
        __syncthreads();
        if (tid < NBIN) scanb[tid] += t;
        __syncthreads();
    }
    if (tid < NBIN) {
        const int excl = scanb[tid] - h;
        if (!isQ) {
            boff[(size_t)b * (NBIN + 1) + tid] = excl;
            if (tid == NBIN - 1) boff[(size_t)b * (NBIN + 1) + NBIN] = n;
        }
        hist[tid] = excl;
    }
    __syncthreads();
    for (int i = tid; i < n; i += BTH1) {
        const float x = P[i * 3], y = P[i * 3 + 1], z = P[i * 3 + 2];
        const int c = bin1(x);
        const int pos = atomicAdd(&hist[c], 1);
        if (isQ) {
            qord[(size_t)b * nb + pos] = i;
        } else {
            float pn;
            {
#pragma clang fp contract(off)
                pn = (x * x + y * y) + z * z;  // matches np.sum(known*known,-1)
            }
            ps[(size_t)b * mb + pos]   = make_float4(x, y, z, pn);
            pidx[(size_t)b * mb + pos] = i;    // original (tie-break) index
        }
    }
}

// ===================== phase A: fixed-window, per-query resolve (r11-proven) ==========
#define QWA  8                // queries per wave (lane&7 = query)
#define SWA  8                // sides (lane>>3), stride-8 interleave -> conflict-free
#define WVBA 4                // waves per block
#define WTHA (WVBA * 64)      // 256 threads
#define QPBA (WVBA * QWA)     // 32 queries per block
#define CHA  64               // candidates staged per chunk

extern "C" __global__ void __launch_bounds__(WTHA)
knn_phaseA(const float* __restrict__ nxyz, const float* __restrict__ feats,
           const int* __restrict__ qord, const int* __restrict__ boff,
           const float4* __restrict__ ps, const int* __restrict__ pidx,
           float* __restrict__ out, int* __restrict__ ovf, float* __restrict__ ovf_ub,
           int* __restrict__ ovf_cnt, int mb, int nb, int C)
{
    __shared__ float4 sP[WVBA][CHA];
    __shared__ int    sI[WVBA][CHA];

    const int tid  = threadIdx.x;
    const int w    = tid >> 6;
    const int l    = tid & 63;
    const int qi   = l & 7;
    const int side = l >> 3;           // 0..7
    const int wid  = blockIdx.x * WVBA + w;
    const int q0   = wid * QWA;
    const int b    = q0 / nb;

    const int qloc = qord[q0 + qi];
    const int row  = b * nb + qloc;
    const float qx = nxyz[(size_t)row * 3 + 0];
    const float qy = nxyz[(size_t)row * 3 + 1];
    const float qz = nxyz[(size_t)row * 3 + 2];
    float qq;
    {
#pragma clang fp contract(off)
        qq = (qx * qx + qy * qy) + qz * qz;    // matches np.sum(query*query,-1)
    }

    // wave x-range (sides duplicate queries -> full butterfly fine)
    float mn = qx, mx = qx;
#pragma unroll
    for (int m = 1; m < 64; m <<= 1) {
        mn = fminf(mn, __shfl_xor(mn, m, 64));
        mx = fmaxf(mx, __shfl_xor(mx, m, 64));
    }

    const int*    boffb = boff + (size_t)b * (NBIN + 1);
    const float4* psb   = ps   + (size_t)b * mb;
    const int*    pib   = pidx + (size_t)b * mb;

    unsigned long long k0 = ~0ull, k1 = ~0ull, k2 = ~0ull;

    // one-chunk-ahead staging (proven schedule)
    float4 rP;
    int    rI = 0;
    bool   rV = false;
    auto issue = [&](int base, int hi) {
        const int cand = base + l;
        rV = cand < hi;
        if (rV) { rP = psb[cand]; rI = pib[cand]; }
    };
    auto commit = [&]() {
        if (rV) { sP[w][l] = rP; sI[w][l] = rI; }
    };
    auto process = [&](int cnt) {
#pragma unroll
        for (int u = 0; u < CHA / SWA; ++u) {
            const int j = side + u * SWA;          // stride-8: conflict-free broadcast
            if (j < cnt) {
                const float4 Pt = sP[w][j];
                const int    pi = sI[w][j];
                const float dot = fmaf(qz, Pt.z, fmaf(qy, Pt.y, qx * Pt.x));
                const float d2  = fmaf(-2.0f, dot, qq) + Pt.w;  // EXACT ref rounding
                const unsigned long long key =
                    ((unsigned long long)f2sort(d2) << 32) | (unsigned)pi;
                if (key < k2) {                    // rare after warm-up
                    const bool c0 = key < k0, c1 = key < k1;
                    k2 = c1 ? k1 : key;
                    k1 = c0 ? k0 : (c1 ? key : k1);
                    k0 = c0 ? key : k0;
                }
            }
        }
    };

    // fixed window [mn-AWIN, mx+AWIN]
    const int blo = bin1(mn - AWIN);
    const int bhi = bin1(mx + AWIN);
    {
        const int lo = boffb[blo], hi = boffb[bhi + 1];
        if (lo < hi) {
            issue(lo, hi);
            for (int base = lo; base < hi; base += CHA) {
                commit();
                if (base + CHA < hi) issue(base + CHA, hi);
                process(min(CHA, hi - base));
            }
        }
    }

    // 8-side butterfly merge (xor 8,16,32) -> every lane holds window top-3
    unsigned long long m0 = k0, m1 = k1, m2 = k2;
#pragma unroll
    for (int mk = 8; mk <= 32; mk <<= 1) {
        const unsigned long long t0 = shfl_xor_u64(m0, mk);
        const unsigned long long t1 = shfl_xor_u64(m1, mk);
        const unsigned long long t2 = shfl_xor_u64(m2, mk);
        ins3k(t0, m0, m1, m2); ins3k(t1, m0, m1, m2); ins3k(t2, m0, m1, m2);
    }

    // per-query provability: everything outside window is farther than ub
    const unsigned h2 = (unsigned)(m2 >> 32);
    const float ub = (h2 == 0xFFFFFFFFu) ? INFINITY : sort2f(h2);
    const float eL = fmaf(0.25f, (float)blo, -BEXT);       // exact bin edges
    const float eR = fmaf(0.25f, (float)(bhi + 1), -BEXT);
    const float gL = qx - eL;
    const float gR = eR - qx;
    const bool okL = (blo == 0)        || (gL * gL > ub + WSLACK);
    const bool okR = (bhi >= NBIN - 1) || (gR * gR > ub + WSLACK);
    const bool resolved = okL && okR && (h2 != 0xFFFFFFFFu);

    // append unresolved queries (one vote per query: side 0 == lanes 0..7)
    const bool need = (side == 0) && !resolved;
    const unsigned long long bm = __ballot(need);
    if (bm) {
        const int rank = __popcll(bm & ((1ull << l) - 1ull));
        const int tot  = __popcll(bm);
        const int lead = __ffsll((unsigned long long)bm) - 1;
        int base = 0;
        if (l == lead) base = atomicAdd(&ovf_cnt[b], tot);
        base = __shfl(base, lead, 64);
        if (need) {
            ovf[(size_t)b * nb + base + rank]    = row;
            ovf_ub[(size_t)b * nb + base + rank] = ub;   // valid UB on true 3rd-NN d2
        }
    }

    // weights for resolved queries
    const float d0  = sort2f((unsigned)(m0 >> 32));
    const float d1  = sort2f((unsigned)(m1 >> 32));
    const float d2v = sort2f((unsigned)(m2 >> 32));
    const float da = sqrtf(fmaxf(d0, 0.0f));
    const float db = sqrtf(fmaxf(d1, 0.0f));
    const float dc = sqrtf(fmaxf(d2v, 0.0f));
    const float ra = 1.0f / (da + 1e-8f);
    const float rb = 1.0f / (db + 1e-8f);
    const float rc = 1.0f / (dc + 1e-8f);
    float rs;
    {
#pragma clang fp contract(off)
        rs = (ra + rb) + rc;
    }
    const float wa = ra / rs, wb = rb / rs, wc = rc / rs;
    const int   ia = b * mb + (int)(unsigned)(m0 & 0xFFFFFFFFu);
    const int   ib = b * mb + (int)(unsigned)(m1 & 0xFFFFFFFFu);
    const int   ic = b * mb + (int)(unsigned)(m2 & 0xFFFFFFFFu);

    // fused interpolation: shfl-broadcast per query (lane q == side-0 of query q)
    for (int q = 0; q < QWA; ++q) {
        if (__shfl((int)resolved, q, 64) == 0) continue;
        const float wa_ = __shfl(wa, q, 64);
        const float wb_ = __shfl(wb, q, 64);
        const float wc_ = __shfl(wc, q, 64);
        const int   ia_ = __shfl(ia, q, 64);
        const int   ib_ = __shfl(ib, q, 64);
        const int   ic_ = __shfl(ic, q, 64);
        const int   rw_ = __shfl(row, q, 64);
        const size_t ga = (size_t)ia_ * C;
        const size_t gb = (size_t)ib_ * C;
        const size_t gc = (size_t)ic_ * C;
        const size_t go = (size_t)rw_ * C;
        for (int ch = l; ch < C; ch += 64) {
            out[go + ch] = wa_ * feats[ga + ch] + wb_ * feats[gb + ch] + wc_ * feats[gc + ch];
        }
    }
}

// ===================== phase B2: one wave per overflow query, ub-bounded window =======
#define WPBB 8                // waves per block
#define BTH2 (WPBB * 64)      // 512 threads

extern "C" __global__ void __launch_bounds__(BTH2)
knn_phaseB2(const float* __restrict__ nxyz, const float* __restrict__ feats,
            const int* __restrict__ ovf, const float* __restrict__ ovf_ub,
            const int* __restrict__ ovf_cnt, const int* __restrict__ boff,
            const float4* __restrict__ ps, const int* __restrict__ pidx,
            float* __restrict__ out, int mb, int nb, int C)
{
    const int tid  = threadIdx.x;
    const int w    = tid >> 6;
    const int l    = tid & 63;
    const int bpb  = nb / WPBB;                 // blocks per batch (capacity)
    const int bb   = (int)blockIdx.x / bpb;
    const int slot = ((int)blockIdx.x % bpb) * WPBB + w;
    const int cnt  = ovf_cnt[bb];
    if (slot >= cnt) return;                    // wave-uniform exit

    const int   row = ovf[(size_t)bb * nb + slot];
    const float ub  = ovf_ub[(size_t)bb * nb + slot];
    const float qx = nxyz[(size_t)row * 3 + 0];
    const float qy = nxyz[(size_t)row * 3 + 1];
    const float qz = nxyz[(size_t)row * 3 + 2];
    float qq;
    {
#pragma clang fp contract(off)
        qq = (qx * qx + qy * qy) + qz * qz;     // matches np.sum(query*query,-1)
    }

    // ub is an upper bound on the true 3rd-NN d2 -> points with (px-qx)^2 > ub+2*WSLACK
    // are provably excluded (same fp-slop proof as phaseA's window bound)
    int blo = 0, bhi = NBIN - 1;
    if (ub < 1e30f) {
        const float r = sqrtf(ub + 2.0f * WSLACK);
        blo = bin1(qx - r);
        bhi = bin1(qx + r);
    }
    const int*    boffb = boff + (size_t)bb * (NBIN + 1);
    const float4* psb   = ps   + (size_t)bb * mb;
    const int*    pib   = pidx + (size_t)bb * mb;
    const int lo = boffb[blo], hi = boffb[bhi + 1];

    unsigned long long k0 = ~0ull, k1 = ~0ull, k2 = ~0ull;
    // 64 lanes split the candidate range: coalesced, independent loads, no LDS
#pragma unroll 4
    for (int t = lo + l; t < hi; t += 64) {
        const float4 Pt = psb[t];
        const int    pi = pib[t];
        const float dot = fmaf(qz, Pt.z, fmaf(qy, Pt.y, qx * Pt.x));
        const float d2  = fmaf(-2.0f, dot, qq) + Pt.w;   // EXACT reference rounding
        const unsigned long long key =
            ((unsigned long long)f2sort(d2) << 32) | (unsigned)pi;
        if (key < k2) {
            const bool c0 = key < k0, c1 = key < k1;
            k2 = c1 ? k1 : key;
            k1 = c0 ? k0 : (c1 ? key : k1);
            k0 = c0 ? key : k0;
        }
    }

    // 64-lane butterfly merge -> every lane holds the exact top-3
#pragma unroll
    for (int m = 1; m < 64; m <<= 1) {
        const unsigned long long t0 = shfl_xor_u64(k0, m);
        const unsigned long long t1 = shfl_xor_u64(k1, m);
        const unsigned long long t2 = shfl_xor_u64(k2, m);
        ins3k(t0, k0, k1, k2); ins3k(t1, k0, k1, k2); ins3k(t2, k0, k1, k2);
    }

    // weights (reference: sqrt(max(d2,0)), recip(+1e-8), normalize)
    const float d0  = sort2f((unsigned)(k0 >> 32));
    const float d1  = sort2f((unsigned)(k1 >> 32));
    const float d2v = sort2f((unsigned)(k2 >> 32));
    const float da = sqrtf(fmaxf(d0, 0.0f));
    const float db = sqrtf(fmaxf(d1, 0.0f));
    const float dc = sqrtf(fmaxf(d2v, 0.0f));
    const float ra = 1.0f / (da + 1e-8f);
    const float rb = 1.0f / (db + 1e-8f);
    const float rc = 1.0f / (dc + 1e-8f);
    float rs;
    {
#pragma clang fp contract(off)
        rs = (ra + rb) + rc;
    }
    const float wa = ra / rs, wb = rb / rs, wc = rc / rs;
    const size_t ga = (size_t)(bb * mb + (int)(unsigned)(k0 & 0xFFFFFFFFu)) * C;
    const size_t gb = (size_t)(bb * mb + (int)(unsigned)(k1 & 0xFFFFFFFFu)) * C;
    const size_t gc = (size_t)(bb * mb + (int)(unsigned)(k2 & 0xFFFFFFFFu)) * C;
    const size_t go = (size_t)row * C;
    for (int ch = l; ch < C; ch += 64) {
        out[go + ch] = wa * feats[ga + ch] + wb * feats[gb + ch] + wc * feats[gc + ch];
    }
}

// ===================== fallback: round-5 brute (proven, shape-general) =====================
#define THREADS 512
#define WAVES   8
#define RQ      2
#define QPB     128
#define CHUNK   2048

extern "C" __global__ void __launch_bounds__(THREADS)
knn3_v5(const float* __restrict__ xyz,
        const float* __restrict__ new_xyz,
        const float* __restrict__ feats,
        float* __restrict__ out,
        int mb, int nb, int C)
{
    extern __shared__ float smem[];
    float4* s_pts = (float4*)smem;
    const int tid = threadIdx.x;
    const int w   = tid >> 6;
    const int l   = tid & 63;
    const int block_q0 = blockIdx.x * QPB;
    const int batch    = block_q0 / nb;
    const int known0   = batch * mb;

    float qx[RQ], qy[RQ], qz[RQ], qq[RQ];
#pragma unroll
    for (int r = 0; r < RQ; ++r) {
        const int gq = block_q0 + r * 64 + l;
        qx[r] = new_xyz[(size_t)gq * 3 + 0];
        qy[r] = new_xyz[(size_t)gq * 3 + 1];
        qz[r] = new_xyz[(size_t)gq * 3 + 2];
        {
#pragma clang fp contract(off)
            qq[r] = (qx[r] * qx[r] + qy[r] * qy[r]) + qz[r] * qz[r];
        }
    }
    float b0[RQ], b1[RQ], b2[RQ];
    int   i0[RQ], i1[RQ], i2[RQ];
#pragma unroll
    for (int r = 0; r < RQ; ++r) {
        b0[r] = INFINITY; b1[r] = INFINITY; b2[r] = INFINITY;
        i0[r] = 0; i1[r] = 0; i2[r] = 0;
    }
    const int nch = (mb + CHUNK - 1) / CHUNK;
    for (int c = 0; c < nch; ++c) {
        const int base = c * CHUNK;
        const int cnt  = min(CHUNK, mb - base);
        if (c > 0) __syncthreads();
        const float* src = xyz + (size_t)(known0 + base) * 3;
        for (int p = tid; p < cnt; p += THREADS) {
            const float px = src[p * 3 + 0];
            const float py = src[p * 3 + 1];
            const float pz = src[p * 3 + 2];
            float pn;
            {
#pragma clang fp contract(off)
                pn = (px * px + py * py) + pz * pz;
            }
            s_pts[p] = make_float4(px, py, pz, pn);
        }
        __syncthreads();
        const int lo = (w * cnt) / WAVES;
        const int hi = ((w + 1) * cnt) / WAVES;
#pragma unroll 4
        for (int p = lo; p < hi; ++p) {
            const float4 P = s_pts[p];
            const int gp = base + p;
#pragma unroll
            for (int r = 0; r < RQ; ++r) {
                const float dot = fmaf(qz[r], P.z, fmaf(qy[r], P.y, qx[r] * P.x));
                const float d2  = fmaf(-2.0f, dot, qq[r]) + P.w;
                const bool c0 = d2 < b0[r];
                const bool c1 = d2 < b1[r];
                const bool c2 = d2 < b2[r];
                const float n0 = fminf(d2, b0[r]);
                const float n1 = __builtin_amdgcn_fmed3f(d2, b0[r], b1[r]);
                const float n2 = __builtin_amdgcn_fmed3f(d2, b1[r], b2[r]);
                const int  j0 = c0 ? gp : i0[r];
                const int  j1 = c0 ? i0[r] : (c1 ? gp : i1[r]);
                const int  j2 = c1 ? i1[r] : (c2 ? gp : i2[r]);
                b0[r] = n0; b1[r] = n1; b2[r] = n2;
                i0[r] = j0; i1[r] = j1; i2[r] = j2;
            }
        }
    }
    __syncthreads();
    float* sB  = smem;
    int*   sI  = (int*)smem + 3 * WAVES * QPB;
    float* sFW = smem + 6 * WAVES * QPB;
    int*   sFI = (int*)sFW + 3 * QPB;
#pragma unroll
    for (int r = 0; r < RQ; ++r) {
        const int qb = r * 64 + l;
        sB[(0 * WAVES + w) * QPB + qb] = b0[r];
        sB[(1 * WAVES + w) * QPB + qb] = b1[r];
        sB[(2 * WAVES + w) * QPB + qb] = b2[r];
        sI[(0 * WAVES + w) * QPB + qb] = i0[r];
        sI[(1 * WAVES + w) * QPB + qb] = i1[r];
        sI[(2 * WAVES + w) * QPB + qb] = i2[r];
    }
    __syncthreads();
    if (tid < QPB) {
        float mv0 = sB[(0 * WAVES) * QPB + tid];
        float mv1 = sB[(1 * WAVES) * QPB + tid];
        float mv2 = sB[(2 * WAVES) * QPB + tid];
        int   mi0 = sI[(0 * WAVES) * QPB + tid];
        int   mi1 = sI[(1 * WAVES) * QPB + tid];
        int   mi2 = sI[(2 * WAVES) * QPB + tid];
        for (int c = 1; c < WAVES; ++c) {
#pragma unroll
            for (int kk = 0; kk < 3; ++kk) {
                const float x  = sB[(kk * WAVES + c) * QPB + tid];
                const int   xi = sI[(kk * WAVES + c) * QPB + tid];
                const bool c0 = (x < mv0) || (x == mv0 && xi < mi0);
                const bool c1 = (x < mv1) || (x == mv1 && xi < mi1);
                const bool c2 = (x < mv2) || (x == mv2 && xi < mi2);
                const float n2 = c1 ? mv1 : (c2 ? x : mv2);
                const int   j2 = c1 ? mi1 : (c2 ? xi : mi2);
                const float n1 = c0 ? mv0 : (c1 ? x : mv1);
                const int   j1 = c0 ? mi0 : (c1 ? xi : mi1);
                const float n0 = c0 ? x : mv0;
                const int   j0 = c0 ? xi : mi0;
                mv0 = n0; mv1 = n1; mv2 = n2;
                mi0 = j0; mi1 = j1; mi2 = j2;
            }
        }
        const float da = sqrtf(fmaxf(mv0, 0.0f));
        const float db = sqrtf(fmaxf(mv1, 0.0f));
        const float dc = sqrtf(fmaxf(mv2, 0.0f));
        const float ra = 1.0f / (da + 1e-8f);
        const float rb = 1.0f / (db + 1e-8f);
        const float rc = 1.0f / (dc + 1e-8f);
        float rsum;
        {
#pragma clang fp contract(off)
            rsum = (ra + rb) + rc;
        }
        sFW[0 * QPB + tid] = ra / rsum;
        sFW[1 * QPB + tid] = rb / rsum;
        sFW[2 * QPB + tid] = rc / rsum;
        sFI[0 * QPB + tid] = known0 + mi0;
        sFI[1 * QPB + tid] = known0 + mi1;
        sFI[2 * QPB + tid] = known0 + mi2;
    }
    __syncthreads();
    const int qpw = QPB / WAVES;
    for (int j = 0; j < qpw; ++j) {
        const int qi2 = w * qpw + j;
        const float wa = sFW[0 * QPB + qi2];
        const float wb = sFW[1 * QPB + qi2];
        const float wc = sFW[2 * QPB + qi2];
        const size_t ga = (size_t)sFI[0 * QPB + qi2] * C;
        const size_t gb = (size_t)sFI[1 * QPB + qi2] * C;
        const size_t gc = (size_t)sFI[2 * QPB + qi2] * C;
        const size_t go = (size_t)(block_q0 + qi2) * C;
        for (int ch = l; ch < C; ch += 64) {
            out[go + ch] = wa * feats[ga + ch] + wb * feats[gb + ch] + wc * feats[gc + ch];
        }
    }
}

#define FQPB 256
extern "C" __global__ void __launch_bounds__(FQPB)
knn3_fallback(const float* __restrict__ xyz,
              const float* __restrict__ new_xyz,
              const float* __restrict__ feats,
              float* __restrict__ out,
              int mb, int nb, int C)
{
    extern __shared__ float4 s_pts[];
    const int tid      = threadIdx.x;
    const int block_q0 = blockIdx.x * FQPB;
    const int batch    = block_q0 / nb;
    const int known0   = batch * mb;
    for (int p = tid; p < mb; p += FQPB) {
        const float px = xyz[(size_t)(known0 + p) * 3 + 0];
        const float py = xyz[(size_t)(known0 + p) * 3 + 1];
        const float pz = xyz[(size_t)(known0 + p) * 3 + 2];
        float pn;
        {
#pragma clang fp contract(off)
            pn = (px * px + py * py) + pz * pz;
        }
        s_pts[p] = make_float4(px, py, pz, pn);
    }
    __syncthreads();
    const int gq = block_q0 + tid;
    const float qx = new_xyz[(size_t)gq * 3 + 0];
    const float qy = new_xyz[(size_t)gq * 3 + 1];
    const float qz = new_xyz[(size_t)gq * 3 + 2];
    float qq;
    {
#pragma clang fp contract(off)
        qq = (qx * qx + qy * qy) + qz * qz;
    }
    float b0 = INFINITY, b1 = INFINITY, b2 = INFINITY;
    int   i0 = 0, i1 = 0, i2 = 0;
#pragma unroll 8
    for (int p = 0; p < mb; ++p) {
        const float4 P = s_pts[p];
        const float dot = fmaf(qz, P.z, fmaf(qy, P.y, qx * P.x));
        const float d2  = fmaf(-2.0f, dot, qq) + P.w;
        const bool c0 = d2 < b0;
        const bool c1 = d2 < b1;
        const bool c2 = d2 < b2;
        b2 = c1 ? b1 : (c2 ? d2 : b2);
        i2 = c1 ? i1 : (c2 ? p  : i2);
        b1 = c0 ? b0 : (c1 ? d2 : b1);
        i1 = c0 ? i0 : (c1 ? p  : i1);
        b0 = c0 ? d2 : b0;
        i0 = c0 ? p  : i0;
    }
    const float da = sqrtf(fmaxf(b0, 0.0f));
    const float db = sqrtf(fmaxf(b1, 0.0f));
    const float dc = sqrtf(fmaxf(b2, 0.0f));
    const float ra = 1.0f / (da + 1e-8f);
    const float rb = 1.0f / (db + 1e-8f);
    const float rc = 1.0f / (dc + 1e-8f);
    float rsum;
    {
#pragma clang fp contract(off)
        rsum = (ra + rb) + rc;
    }
    const float wa = ra / rsum, wb = rb / rsum, wc = rc / rsum;
    const size_t ga = (size_t)(known0 + i0) * C;
    const size_t gb = (size_t)(known0 + i1) * C;
    const size_t gc = (size_t)(known0 + i2) * C;
    const size_t go = (size_t)gq * C;
    for (int ch = 0; ch < C; ++ch) {
        out[go + ch] = wa * feats[ga + ch] + wb * feats[gb + ch] + wc * feats[gc + ch];
    }
}

extern "C" void kernel_launch(void* const* d_in, const int* in_sizes, int n_in,
                              void* d_out, int out_size, void* d_ws, size_t ws_size,
                              hipStream_t stream) {
    const float* xyz     = (const float*)d_in[0];
    const float* new_xyz = (const float*)d_in[2];
    const float* feats   = (const float*)d_in[4];
    float*       out     = (float*)d_out;

    const int n_known = in_sizes[0] / 3;
    const int B       = in_sizes[1];
    const int n_query = in_sizes[2] / 3;
    const int C       = in_sizes[4] / n_known;
    const int mb      = n_known / B;
    const int nb      = n_query / B;

    // workspace layout
    char* wp = (char*)d_ws;
    float4* ps      = (float4*)wp;  wp += (size_t)B * mb * sizeof(float4);
    int*    pidx    = (int*)wp;     wp += (size_t)B * mb * sizeof(int);
    int*    qord    = (int*)wp;     wp += (size_t)B * nb * sizeof(int);
    int*    boff    = (int*)wp;     wp += (size_t)B * (NBIN + 1) * sizeof(int);
    int*    ovf     = (int*)wp;     wp += (size_t)B * nb * sizeof(int);
    float*  ovf_ub  = (float*)wp;   wp += (size_t)B * nb * sizeof(float);
    int*    ovf_cnt = (int*)wp;     wp += (size_t)B * sizeof(int);
    const size_t need = (size_t)(wp - (char*)d_ws);

    if (ws_size >= need && (nb % QWA) == 0 && (n_query % QPBA) == 0 &&
        (nb % WPBB) == 0 && mb >= 3 && B <= BTH1) {
        build1d<<<2 * B, BTH1, 0, stream>>>(xyz, new_xyz, mb, nb, ps, pidx, qord,
                                            boff, ovf_cnt);
        knn_phaseA<<<n_query / QPBA, WTHA, 0, stream>>>(
            new_xyz, feats, qord, boff, ps, pidx, out, ovf, ovf_ub, ovf_cnt,
            mb, nb, C);
        knn_phaseB2<<<B * (nb / WPBB), BTH2, 0, stream>>>(
            new_xyz, feats, ovf, ovf_ub, ovf_cnt, boff, ps, pidx, out, mb, nb, C);
    } else if ((nb % QPB) == 0) {
        const size_t smem_chunk = (size_t)CHUNK * sizeof(float4);
        const size_t smem_merge = (size_t)(6 * WAVES * QPB + 6 * QPB) * sizeof(float);
        const size_t shmem = smem_chunk > smem_merge ? smem_chunk : smem_merge;
        knn3_v5<<<n_query / QPB, THREADS, shmem, stream>>>(
            xyz, new_xyz, feats, out, mb, nb, C);
    } else {
        const size_t shmem = (size_t)mb * sizeof(float4);
        knn3_fallback<<<(n_query + FQPB - 1) / FQPB, FQPB, shmem, stream>>>(
            xyz, new_xyz, feats, out, mb, nb, C);
    }
}